// Round 5
// baseline (1360.411 us; speedup 1.0000x reference)
//
#include <hip/hip_runtime.h>
#include <hip/hip_bf16.h>
#include <math.h>

#define B_   2
#define S_   2048
#define H_   2048
#define NH   16
#define HD   128
#define ROWS (B_ * S_)   // 4096
#define F3   (3 * H_)    // 6144
#define KS   2048        // inner dim of both projection GEMMs (per split term)

typedef _Float16 f16x8 __attribute__((ext_vector_type(8)));
typedef float    f32x4  __attribute__((ext_vector_type(4)));
typedef float    f32x16 __attribute__((ext_vector_type(16)));

union H2 { unsigned u; _Float16 h[2]; };
union H4 { ushort4 s4; _Float16 h[4]; };

__device__ __forceinline__ void gl_lds16(const void* g, void* l) {
  __builtin_amdgcn_global_load_lds(
      (const __attribute__((address_space(1))) void*)g,
      (__attribute__((address_space(3))) void*)l, 16, 0, 0);
}

// ---------------------------------------------------------------------------
// fp8 e4m3fn RNE quantization -> representable value (exact in fp16)
// ---------------------------------------------------------------------------
__device__ __forceinline__ float quant_e4m3(float x) {
  float ax = fabsf(x);
  float q;
  if (ax < 0.015625f) {
    q = rintf(ax * 512.0f) * (1.0f / 512.0f);
  } else {
    unsigned eb = __float_as_uint(ax) & 0x7f800000u;
    float quantum = __uint_as_float(eb - (3u << 23));      // 2^(e-3)
    q = rintf(ax / quantum) * quantum;
    if (q > 448.0f) q = 448.0f;
  }
  return copysignf(q, x);
}

// ---------------------------------------------------------------------------
// fp32 -> fp16 hi/lo split, elementwise (for A operand: x)
// ---------------------------------------------------------------------------
__global__ __launch_bounds__(256) void split_ab(
    const float* __restrict__ in, _Float16* __restrict__ hi,
    _Float16* __restrict__ lo) {
  const size_t i = (size_t)blockIdx.x * 256 + threadIdx.x;
  float4 v = ((const float4*)in)[i];
  H4 h, l;
  h.h[0] = (_Float16)v.x; l.h[0] = (_Float16)(v.x - (float)h.h[0]);
  h.h[1] = (_Float16)v.y; l.h[1] = (_Float16)(v.y - (float)h.h[1]);
  h.h[2] = (_Float16)v.z; l.h[2] = (_Float16)(v.z - (float)h.h[2]);
  h.h[3] = (_Float16)v.w; l.h[3] = (_Float16)(v.w - (float)h.h[3]);
  ((ushort4*)hi)[i] = h.s4;
  ((ushort4*)lo)[i] = l.s4;
}

// ---------------------------------------------------------------------------
// fp32 K x N -> fp16 hi/lo, TRANSPOSED to N x K (for B operands: W_qkv, W_out)
// ---------------------------------------------------------------------------
__global__ __launch_bounds__(256) void split_tr(
    const float* __restrict__ in, _Float16* __restrict__ hi,
    _Float16* __restrict__ lo, int K, int N) {
  __shared__ _Float16 ht[64][72];
  __shared__ _Float16 lt[64][72];
  const int t = threadIdx.x;
  const int n0 = blockIdx.x * 64, k0 = blockIdx.y * 64;
#pragma unroll
  for (int p = 0; p < 4; p++) {
    const int k = p * 16 + (t >> 4);
    const int n = (t & 15) * 4;
    float4 v = *(const float4*)(in + (size_t)(k0 + k) * N + n0 + n);
    _Float16 h0 = (_Float16)v.x, h1 = (_Float16)v.y,
             h2 = (_Float16)v.z, h3 = (_Float16)v.w;
    ht[n + 0][k] = h0; lt[n + 0][k] = (_Float16)(v.x - (float)h0);
    ht[n + 1][k] = h1; lt[n + 1][k] = (_Float16)(v.y - (float)h1);
    ht[n + 2][k] = h2; lt[n + 2][k] = (_Float16)(v.z - (float)h2);
    ht[n + 3][k] = h3; lt[n + 3][k] = (_Float16)(v.w - (float)h3);
  }
  __syncthreads();
#pragma unroll
  for (int it = 0; it < 2; it++) {
    const int idx = it * 256 + t;
    const int r = idx >> 3, c = (idx & 7) * 8;
    *(uint4*)(hi + (size_t)(n0 + r) * K + k0 + c) = *(const uint4*)&ht[r][c];
    *(uint4*)(lo + (size_t)(n0 + r) * K + k0 + c) = *(const uint4*)&lt[r][c];
  }
}

// ---------------------------------------------------------------------------
// MFMA split-fp16 GEMM: C[M,N] = A @ B^T over K' = 3*KS (unchanged, at the
// m97-structure plateau ~826 TF)
// ---------------------------------------------------------------------------
__global__ __launch_bounds__(256) void gemm_split(
    const _Float16* __restrict__ Ahi, const _Float16* __restrict__ Alo,
    const _Float16* __restrict__ Bthi, const _Float16* __restrict__ Btlo,
    float* __restrict__ C, const float* __restrict__ bias,
    int N, int has_bias) {
  __shared__ _Float16 Asm[128 * 32];
  __shared__ _Float16 Bsm[128 * 32];
  const int t = threadIdx.x;
  const int wave = t >> 6, lane = t & 63;
  const int l15 = lane & 15, g = lane >> 4;
  const int row0 = blockIdx.y * 128, col0 = blockIdx.x * 128;
  const int wm = wave & 1, wn = wave >> 1;
  const int srow = wave * 32 + (lane >> 2);
  const int schunk = (lane & 3) * 8;

  f32x4 acc[4][4] = {};

  for (int kc = 0; kc < 3 * (KS / 32); kc++) {
    const int phase = kc >> 6;
    const int klocal = (kc & 63) << 5;
    const _Float16* As = (phase == 2) ? Alo : Ahi;
    const _Float16* Bs = (phase == 1) ? Btlo : Bthi;
    __syncthreads();
#pragma unroll
    for (int i = 0; i < 2; i++) {
      gl_lds16(As + (size_t)(row0 + srow + i * 16) * KS + klocal + schunk,
               Asm + (wave * 32 + i * 16) * 32);
      gl_lds16(Bs + (size_t)(col0 + srow + i * 16) * KS + klocal + schunk,
               Bsm + (wave * 32 + i * 16) * 32);
    }
    __syncthreads();
    f16x8 af[4], bf[4];
#pragma unroll
    for (int i = 0; i < 4; i++)
      af[i] = *(const f16x8*)(Asm + (wm * 64 + i * 16 + l15) * 32 + g * 8);
#pragma unroll
    for (int j = 0; j < 4; j++)
      bf[j] = *(const f16x8*)(Bsm + (wn * 64 + j * 16 + l15) * 32 + g * 8);
#pragma unroll
    for (int i = 0; i < 4; i++)
#pragma unroll
      for (int j = 0; j < 4; j++)
        acc[i][j] = __builtin_amdgcn_mfma_f32_16x16x32_f16(af[i], bf[j], acc[i][j], 0, 0, 0);
  }

#pragma unroll
  for (int j = 0; j < 4; j++) {
    const int col = col0 + wn * 64 + j * 16 + l15;
    const float bv = has_bias ? bias[col] : 0.0f;
#pragma unroll
    for (int i = 0; i < 4; i++) {
      const int rbase = row0 + wm * 64 + i * 16 + g * 4;
#pragma unroll
      for (int r = 0; r < 4; r++)
        C[(size_t)(rbase + r) * N + col] = acc[i][j][r] + bv;
    }
  }
}

// ---------------------------------------------------------------------------
// Global max|.| per q/k/v segment
// ---------------------------------------------------------------------------
__global__ __launch_bounds__(256) void maxabs_kernel(
    const float* __restrict__ qkv, unsigned* __restrict__ mx) {
  __shared__ float red[256];
  const int seg = blockIdx.x % 3;
  const int row = blockIdx.x / 3;
  const float4* p = (const float4*)(qkv + (size_t)row * F3 + seg * 2048);
  float m = 0.0f;
  for (int i = threadIdx.x; i < 512; i += 256) {
    float4 v = p[i];
    m = fmaxf(m, fmaxf(fmaxf(fabsf(v.x), fabsf(v.y)), fmaxf(fabsf(v.z), fabsf(v.w))));
  }
  red[threadIdx.x] = m;
  __syncthreads();
  for (int s = 128; s > 0; s >>= 1) {
    if (threadIdx.x < s) red[threadIdx.x] = fmaxf(red[threadIdx.x], red[threadIdx.x + s]);
    __syncthreads();
  }
  if (threadIdx.x == 0) atomicMax(mx + seg, __float_as_uint(red[0]));
}

// ---------------------------------------------------------------------------
// Quantize Q,K segments -> fp16 exact e4m3 values, [bh][s][d]
// ---------------------------------------------------------------------------
__global__ __launch_bounds__(256) void quant_qk(
    const float* __restrict__ qkv, const unsigned* __restrict__ mx,
    _Float16* __restrict__ q8, _Float16* __restrict__ k8) {
  const size_t base = ((size_t)blockIdx.x * 256 + threadIdx.x) * 4;
  const int row = (int)(base >> 12);
  const int col = (int)(base & 4095);
  const int seg = col >> 11;
  const int c2 = col & 2047;
  const int h = c2 >> 7, d = c2 & 127;
  const int b = row >> 11, s = row & 2047;
  const float scale = __uint_as_float(mx[seg]) / 448.0f;
  float4 v = *(const float4*)(qkv + (size_t)row * F3 + col);
  H4 r;
  r.h[0] = (_Float16)quant_e4m3(v.x / scale);
  r.h[1] = (_Float16)quant_e4m3(v.y / scale);
  r.h[2] = (_Float16)quant_e4m3(v.z / scale);
  r.h[3] = (_Float16)quant_e4m3(v.w / scale);
  _Float16* dst = seg ? k8 : q8;
  const size_t di = ((size_t)((b * NH + h) * S_) + s) * HD + d;
  *(ushort4*)(dst + di) = r.s4;
}

// ---------------------------------------------------------------------------
// Quantize V -> fp16 values stored TRANSPOSED: v8t[bh][d][s]
// ---------------------------------------------------------------------------
__global__ __launch_bounds__(256) void quant_v_t(
    const float* __restrict__ qkv, const unsigned* __restrict__ mx,
    _Float16* __restrict__ v8t) {
  __shared__ _Float16 tile[64 * 72];
  const int t = threadIdx.x;
  const int bt = blockIdx.x;
  const int dtile = bt & 1;
  const int stile = (bt >> 1) & 31;
  const int bh = bt >> 6;
  const int b = bh >> 4, h = bh & 15;
  const int s0 = stile * 64, d0 = dtile * 64;
  const float scale = __uint_as_float(mx[2]) / 448.0f;

#pragma unroll
  for (int r = 0; r < 4; r++) {
    const int s = s0 + r * 16 + (t >> 4);
    const int dl = (t & 15) * 4;
    float4 v = *(const float4*)(qkv + (size_t)(b * S_ + s) * F3 + 4096 + h * HD + d0 + dl);
    tile[(dl + 0) * 72 + r * 16 + (t >> 4)] = (_Float16)quant_e4m3(v.x / scale);
    tile[(dl + 1) * 72 + r * 16 + (t >> 4)] = (_Float16)quant_e4m3(v.y / scale);
    tile[(dl + 2) * 72 + r * 16 + (t >> 4)] = (_Float16)quant_e4m3(v.z / scale);
    tile[(dl + 3) * 72 + r * 16 + (t >> 4)] = (_Float16)quant_e4m3(v.w / scale);
  }
  __syncthreads();
#pragma unroll
  for (int j = 0; j < 2; j++) {
    const int wi = j * 256 + t;
    const int dl = wi >> 3;
    const int sch = (wi & 7) * 8;
    uint4 val = *(const uint4*)(tile + dl * 72 + sch);
    *(uint4*)(v8t + (size_t)bh * (HD * S_) + (size_t)(d0 + dl) * S_ + s0 + sch) = val;
  }
}

// ---------------------------------------------------------------------------
// MFMA flash attention, round-5 rework:
//  * fixed-base softmax: base = row max of FIRST 32-key sub-tile; no alpha,
//    no acc rescale (base cancels in acc/l). fminf clamp guards fp16 range.
//  * 128-thread wg (2 waves), 128 q per wg, grid 512 -> 4 blocks/CU,
//    2 waves/SIMD for MFMA/VALU cross-wave overlap.
//  * epilogue emits fp16 hi/lo split directly (feeds out-proj GEMM).
// ---------------------------------------------------------------------------
__global__ __launch_bounds__(128, 2) void attn_kernel(
    const _Float16* __restrict__ q8, const _Float16* __restrict__ k8,
    const _Float16* __restrict__ v8t, const unsigned* __restrict__ mx,
    _Float16* __restrict__ oHi, _Float16* __restrict__ oLo) {
  __shared__ __align__(16) char ldsb[35840];
  _Float16* Klds  = (_Float16*)ldsb;                 // [64 keys][136]
  _Float16* VTlds = (_Float16*)(ldsb + 17408);       // [128 d][72]

  const int t = threadIdx.x;        // 0..127
  const int wave = t >> 6;          // 0..1
  const int lane = t & 63;
  const int l31 = lane & 31;
  const int hf = lane >> 5;

  const int qt = blockIdx.x & 15;
  const int bh = blockIdx.x >> 4;
  const int b = bh >> 4, h = bh & 15;
  const int q0 = qt * 128;

  const float qs = __uint_as_float(mx[0]) * (1.0f / 448.0f);
  const float ks = __uint_as_float(mx[1]) * (1.0f / 448.0f);
  const float vs = __uint_as_float(mx[2]) * (1.0f / 448.0f);
  const float sfac = qs * ks * 0.08838834764831843f;   // 1/sqrt(128)

  // Q fragments: wave owns 64 q (2 n-tiles of 32)
  f16x8 qf[2][8];
#pragma unroll
  for (int nt = 0; nt < 2; nt++) {
    const _Float16* qp = q8 + ((size_t)(bh * S_) + q0 + wave * 64 + nt * 32 + l31) * HD + hf * 8;
#pragma unroll
    for (int st = 0; st < 8; st++)
      qf[nt][st] = *(const f16x8*)(qp + st * 16);
  }

  f32x16 acc[4][2] = {};
  float m_base[2] = {0.0f, 0.0f};
  float l_run[2] = {0.0f, 0.0f};

  for (int kt = 0; kt < S_ / 64; kt++) {
    const int kt0 = kt * 64;
    __syncthreads();
    // stage K tile [64][136]: 1024 16B-chunks over 128 threads
#pragma unroll
    for (int r = 0; r < 8; r++) {
      const int idx = r * 128 + t;
      const int key = idx >> 4;
      const int dch = (idx & 15) * 8;
      uint4 v = *(const uint4*)(k8 + ((size_t)(bh * S_) + kt0 + key) * HD + dch);
      *(uint4*)(Klds + key * 136 + dch) = v;
    }
    // stage V^T tile [128][72]
#pragma unroll
    for (int r = 0; r < 8; r++) {
      const int idx = r * 128 + t;
      const int d = idx >> 3;
      const int sch = (idx & 7) * 8;
      uint4 v = *(const uint4*)(v8t + (size_t)bh * (HD * S_) + (size_t)d * S_ + kt0 + sch);
      *(uint4*)(VTlds + d * 72 + sch) = v;
    }
    __syncthreads();

#pragma unroll
    for (int sub = 0; sub < 2; sub++) {
      const int ksub = sub * 32;
      // ---- S^T = K . Q^T ----
      f32x16 s[2] = {};
#pragma unroll
      for (int st = 0; st < 8; st++) {
        f16x8 af = *(const f16x8*)(Klds + (ksub + l31) * 136 + st * 16 + hf * 8);
        s[0] = __builtin_amdgcn_mfma_f32_32x32x16_f16(af, qf[0][st], s[0], 0, 0, 0);
        s[1] = __builtin_amdgcn_mfma_f32_32x32x16_f16(af, qf[1][st], s[1], 0, 0, 0);
      }
      // ---- fixed-base softmax weights ----
      f16x8 pf[2][2];
#pragma unroll
      for (int nt = 0; nt < 2; nt++) {
        float p[16];
        if (kt == 0 && sub == 0) {
          float tmax = -3.0e38f;
#pragma unroll
          for (int i = 0; i < 16; i++) {
            p[i] = s[nt][i] * sfac;
            tmax = fmaxf(tmax, p[i]);
          }
          tmax = fmaxf(tmax, __shfl_xor(tmax, 32));
          m_base[nt] = tmax;
          float rs = 0.0f;
#pragma unroll
          for (int i = 0; i < 16; i++) {
            p[i] = __expf(p[i] - tmax);
            rs += p[i];
          }
          l_run[nt] += rs;
        } else {
          const float mb = m_base[nt];
          float rs = 0.0f;
#pragma unroll
          for (int i = 0; i < 16; i++) {
            p[i] = fminf(__expf(fmaf(s[nt][i], sfac, -mb)), 60000.0f);
            rs += p[i];
          }
          l_run[nt] += rs;
        }
        // pack + cross-half exchange -> P^T B-frags (keys ascending)
#pragma unroll
        for (int c = 0; c < 2; c++) {
          const int c8 = c * 8;
          const int sidx = hf ? 0 : 4;
          const int oidx = hf ? 4 : 0;
          H2 s0h, s1h, o0h, o1h;
          s0h.h[0] = (_Float16)p[c8 + sidx];     s0h.h[1] = (_Float16)p[c8 + sidx + 1];
          s1h.h[0] = (_Float16)p[c8 + sidx + 2]; s1h.h[1] = (_Float16)p[c8 + sidx + 3];
          o0h.h[0] = (_Float16)p[c8 + oidx];     o0h.h[1] = (_Float16)p[c8 + oidx + 1];
          o1h.h[0] = (_Float16)p[c8 + oidx + 2]; o1h.h[1] = (_Float16)p[c8 + oidx + 3];
          unsigned r0 = (unsigned)__shfl_xor((int)s0h.u, 32);
          unsigned r1 = (unsigned)__shfl_xor((int)s1h.u, 32);
          unsigned fu[4];
          if (hf == 0) { fu[0] = o0h.u; fu[1] = o1h.u; fu[2] = r0; fu[3] = r1; }
          else         { fu[0] = r0;    fu[1] = r1;    fu[2] = o0h.u; fu[3] = o1h.u; }
          pf[nt][c] = *(f16x8*)fu;
        }
      }
      // ---- O^T += V^T . P^T ----
#pragma unroll
      for (int dt = 0; dt < 4; dt++) {
#pragma unroll
        for (int c = 0; c < 2; c++) {
          f16x8 vf = *(const f16x8*)(VTlds + (dt * 32 + l31) * 72 + ksub + c * 16 + hf * 8);
          acc[dt][0] = __builtin_amdgcn_mfma_f32_32x32x16_f16(vf, pf[0][c], acc[dt][0], 0, 0, 0);
          acc[dt][1] = __builtin_amdgcn_mfma_f32_32x32x16_f16(vf, pf[1][c], acc[dt][1], 0, 0, 0);
        }
      }
    }
  }

  // combine the two half-lane partial sums of l
  l_run[0] += __shfl_xor(l_run[0], 32);
  l_run[1] += __shfl_xor(l_run[1], 32);

  // ---- epilogue: O^T -> O via per-wave LDS transpose; emit fp16 hi/lo ----
  __syncthreads();
  float* scr = (float*)ldsb + wave * 1056;   // 32 x 33 fp32 per wave
#pragma unroll
  for (int dt = 0; dt < 4; dt++) {
#pragma unroll
    for (int nt = 0; nt < 2; nt++) {
      const float f = vs / l_run[nt];
#pragma unroll
      for (int i = 0; i < 16; i++) {
        const int dl = (i & 3) + 8 * (i >> 2) + 4 * hf;
        scr[dl * 33 + l31] = acc[dt][nt][i] * f;
      }
      __syncthreads();
#pragma unroll
      for (int g = 0; g < 4; g++) {
        const int idx = g * 64 + lane;
        const int ql = idx >> 3;
        const int dd = (idx & 7) * 4;
        float4 o;
        o.x = scr[(dd + 0) * 33 + ql];
        o.y = scr[(dd + 1) * 33 + ql];
        o.z = scr[(dd + 2) * 33 + ql];
        o.w = scr[(dd + 3) * 33 + ql];
        H4 hh, ll;
        hh.h[0] = (_Float16)o.x; ll.h[0] = (_Float16)(o.x - (float)hh.h[0]);
        hh.h[1] = (_Float16)o.y; ll.h[1] = (_Float16)(o.y - (float)hh.h[1]);
        hh.h[2] = (_Float16)o.z; ll.h[2] = (_Float16)(o.z - (float)hh.h[2]);
        hh.h[3] = (_Float16)o.w; ll.h[3] = (_Float16)(o.w - (float)hh.h[3]);
        const int qg = q0 + wave * 64 + nt * 32 + ql;
        const size_t ofs = (size_t)(b * S_ + qg) * H_ + h * HD + dt * 32 + dd;
        *(ushort4*)(oHi + ofs) = hh.s4;
        *(ushort4*)(oLo + ofs) = ll.s4;
      }
      __syncthreads();
    }
  }
}

// ---------------------------------------------------------------------------
extern "C" void kernel_launch(void* const* d_in, const int* in_sizes, int n_in,
                              void* d_out, int out_size, void* d_ws, size_t ws_size,
                              hipStream_t stream) {
  const float* x     = (const float*)d_in[0];
  const float* W_qkv = (const float*)d_in[1];
  const float* W_out = (const float*)d_in[2];
  const float* b_out = (const float*)d_in[3];
  float* out = (float*)d_out;

  char* ws = (char*)d_ws;
  // Region 0 [0, 100.66 MB): qkv fp32; later A2 splits (attn output) + B2t
  float*    qkv    = (float*)ws;
  _Float16* A2hi   = (_Float16*)(ws + 33554432);               // 16,777,216 B
  _Float16* A2lo   = (_Float16*)(ws + 50331648);
  _Float16* B2thi  = (_Float16*)(ws + 67108864);               //  8,388,608 B
  _Float16* B2tlo  = (_Float16*)(ws + 75497472);
  // Region 1 [100.66, 151.0 MB): B1t splits, then reused for q8/k8/v8t
  _Float16* B1thi  = (_Float16*)(ws + 100663296);              // 25,165,824 B
  _Float16* B1tlo  = (_Float16*)(ws + 125829120);
  _Float16* q8     = (_Float16*)(ws + 100663296);              // 16,777,216 B
  _Float16* k8     = (_Float16*)(ws + 117440512);
  _Float16* v8t    = (_Float16*)(ws + 134217728);
  // Region 2 [151.0, 184.6 MB): A1 splits
  _Float16* A1hi   = (_Float16*)(ws + 150994944);
  _Float16* A1lo   = (_Float16*)(ws + 167772160);
  unsigned* mx     = (unsigned*)(ws + 184549376);

  hipMemsetAsync(mx, 0, 3 * sizeof(unsigned), stream);

  // split x (A1) and W_qkv^T (B1t)
  split_ab<<<(ROWS * H_) / 1024, 256, 0, stream>>>(x, A1hi, A1lo);
  split_tr<<<dim3(F3 / 64, H_ / 64), 256, 0, stream>>>(W_qkv, B1thi, B1tlo, H_, F3);

  // qkv = x @ W_qkv  (split-fp16 MFMA, K' = 6144)
  gemm_split<<<dim3(F3 / 128, ROWS / 128), 256, 0, stream>>>(
      A1hi, A1lo, B1thi, B1tlo, qkv, nullptr, F3, 0);

  maxabs_kernel<<<ROWS * 3, 256, 0, stream>>>(qkv, mx);
  quant_qk<<<(ROWS * 4096) / 1024, 256, 0, stream>>>(qkv, mx, q8, k8);
  quant_v_t<<<B_ * NH * 32 * 2, 256, 0, stream>>>(qkv, mx, v8t);

  // attention -> writes out-proj A-operand hi/lo directly
  attn_kernel<<<B_ * NH * 16, 128, 0, stream>>>(q8, k8, v8t, mx, A2hi, A2lo);

  // split W_out^T (B2t)
  split_tr<<<dim3(H_ / 64, H_ / 64), 256, 0, stream>>>(W_out, B2thi, B2tlo, H_, H_);

  // out = attn_out @ W_out + b_out
  gemm_split<<<dim3(H_ / 128, ROWS / 128), 256, 0, stream>>>(
      A2hi, A2lo, B2thi, B2tlo, out, b_out, H_, 1);
}

// Round 6
// 1076.118 us; speedup vs baseline: 1.2642x; 1.2642x over previous
//
#include <hip/hip_runtime.h>
#include <hip/hip_bf16.h>
#include <math.h>

#define B_   2
#define S_   2048
#define H_   2048
#define NH   16
#define HD   128
#define ROWS (B_ * S_)   // 4096
#define F3   (3 * H_)    // 6144
#define KS   2048        // inner dim of both projection GEMMs (per split term)

typedef _Float16 f16x8 __attribute__((ext_vector_type(8)));
typedef float    f32x4  __attribute__((ext_vector_type(4)));
typedef float    f32x16 __attribute__((ext_vector_type(16)));

union H2 { unsigned u; _Float16 h[2]; };
union H4 { ushort4 s4; _Float16 h[4]; };

__device__ __forceinline__ void gl_lds16(const void* g, void* l) {
  __builtin_amdgcn_global_load_lds(
      (const __attribute__((address_space(1))) void*)g,
      (__attribute__((address_space(3))) void*)l, 16, 0, 0);
}

// ---------------------------------------------------------------------------
// fp8 e4m3fn RNE quantization -> representable value (exact in fp16)
// ---------------------------------------------------------------------------
__device__ __forceinline__ float quant_e4m3(float x) {
  float ax = fabsf(x);
  float q;
  if (ax < 0.015625f) {
    q = rintf(ax * 512.0f) * (1.0f / 512.0f);
  } else {
    unsigned eb = __float_as_uint(ax) & 0x7f800000u;
    float quantum = __uint_as_float(eb - (3u << 23));      // 2^(e-3)
    q = rintf(ax / quantum) * quantum;
    if (q > 448.0f) q = 448.0f;
  }
  return copysignf(q, x);
}

// ---------------------------------------------------------------------------
// fp32 -> fp16 hi/lo split, elementwise (for A operand: x)
// ---------------------------------------------------------------------------
__global__ __launch_bounds__(256) void split_ab(
    const float* __restrict__ in, _Float16* __restrict__ hi,
    _Float16* __restrict__ lo) {
  const size_t i = (size_t)blockIdx.x * 256 + threadIdx.x;
  float4 v = ((const float4*)in)[i];
  H4 h, l;
  h.h[0] = (_Float16)v.x; l.h[0] = (_Float16)(v.x - (float)h.h[0]);
  h.h[1] = (_Float16)v.y; l.h[1] = (_Float16)(v.y - (float)h.h[1]);
  h.h[2] = (_Float16)v.z; l.h[2] = (_Float16)(v.z - (float)h.h[2]);
  h.h[3] = (_Float16)v.w; l.h[3] = (_Float16)(v.w - (float)h.h[3]);
  ((ushort4*)hi)[i] = h.s4;
  ((ushort4*)lo)[i] = l.s4;
}

// ---------------------------------------------------------------------------
// fp32 K x N -> fp16 hi/lo, TRANSPOSED to N x K (for B operands)
// ---------------------------------------------------------------------------
__global__ __launch_bounds__(256) void split_tr(
    const float* __restrict__ in, _Float16* __restrict__ hi,
    _Float16* __restrict__ lo, int K, int N) {
  __shared__ _Float16 ht[64][72];
  __shared__ _Float16 lt[64][72];
  const int t = threadIdx.x;
  const int n0 = blockIdx.x * 64, k0 = blockIdx.y * 64;
#pragma unroll
  for (int p = 0; p < 4; p++) {
    const int k = p * 16 + (t >> 4);
    const int n = (t & 15) * 4;
    float4 v = *(const float4*)(in + (size_t)(k0 + k) * N + n0 + n);
    _Float16 h0 = (_Float16)v.x, h1 = (_Float16)v.y,
             h2 = (_Float16)v.z, h3 = (_Float16)v.w;
    ht[n + 0][k] = h0; lt[n + 0][k] = (_Float16)(v.x - (float)h0);
    ht[n + 1][k] = h1; lt[n + 1][k] = (_Float16)(v.y - (float)h1);
    ht[n + 2][k] = h2; lt[n + 2][k] = (_Float16)(v.z - (float)h2);
    ht[n + 3][k] = h3; lt[n + 3][k] = (_Float16)(v.w - (float)h3);
  }
  __syncthreads();
#pragma unroll
  for (int it = 0; it < 2; it++) {
    const int idx = it * 256 + t;
    const int r = idx >> 3, c = (idx & 7) * 8;
    *(uint4*)(hi + (size_t)(n0 + r) * K + k0 + c) = *(const uint4*)&ht[r][c];
    *(uint4*)(lo + (size_t)(n0 + r) * K + k0 + c) = *(const uint4*)&lt[r][c];
  }
}

// ---------------------------------------------------------------------------
// MFMA split-fp16 GEMM (unchanged, ~826 TF plateau)
// ---------------------------------------------------------------------------
__global__ __launch_bounds__(256) void gemm_split(
    const _Float16* __restrict__ Ahi, const _Float16* __restrict__ Alo,
    const _Float16* __restrict__ Bthi, const _Float16* __restrict__ Btlo,
    float* __restrict__ C, const float* __restrict__ bias,
    int N, int has_bias) {
  __shared__ _Float16 Asm[128 * 32];
  __shared__ _Float16 Bsm[128 * 32];
  const int t = threadIdx.x;
  const int wave = t >> 6, lane = t & 63;
  const int l15 = lane & 15, g = lane >> 4;
  const int row0 = blockIdx.y * 128, col0 = blockIdx.x * 128;
  const int wm = wave & 1, wn = wave >> 1;
  const int srow = wave * 32 + (lane >> 2);
  const int schunk = (lane & 3) * 8;

  f32x4 acc[4][4] = {};

  for (int kc = 0; kc < 3 * (KS / 32); kc++) {
    const int phase = kc >> 6;
    const int klocal = (kc & 63) << 5;
    const _Float16* As = (phase == 2) ? Alo : Ahi;
    const _Float16* Bs = (phase == 1) ? Btlo : Bthi;
    __syncthreads();
#pragma unroll
    for (int i = 0; i < 2; i++) {
      gl_lds16(As + (size_t)(row0 + srow + i * 16) * KS + klocal + schunk,
               Asm + (wave * 32 + i * 16) * 32);
      gl_lds16(Bs + (size_t)(col0 + srow + i * 16) * KS + klocal + schunk,
               Bsm + (wave * 32 + i * 16) * 32);
    }
    __syncthreads();
    f16x8 af[4], bf[4];
#pragma unroll
    for (int i = 0; i < 4; i++)
      af[i] = *(const f16x8*)(Asm + (wm * 64 + i * 16 + l15) * 32 + g * 8);
#pragma unroll
    for (int j = 0; j < 4; j++)
      bf[j] = *(const f16x8*)(Bsm + (wn * 64 + j * 16 + l15) * 32 + g * 8);
#pragma unroll
    for (int i = 0; i < 4; i++)
#pragma unroll
      for (int j = 0; j < 4; j++)
        acc[i][j] = __builtin_amdgcn_mfma_f32_16x16x32_f16(af[i], bf[j], acc[i][j], 0, 0, 0);
  }

#pragma unroll
  for (int j = 0; j < 4; j++) {
    const int col = col0 + wn * 64 + j * 16 + l15;
    const float bv = has_bias ? bias[col] : 0.0f;
#pragma unroll
    for (int i = 0; i < 4; i++) {
      const int rbase = row0 + wm * 64 + i * 16 + g * 4;
#pragma unroll
      for (int r = 0; r < 4; r++)
        C[(size_t)(rbase + r) * N + col] = acc[i][j][r] + bv;
    }
  }
}

// ---------------------------------------------------------------------------
// Global max|.| per q/k/v segment
// ---------------------------------------------------------------------------
__global__ __launch_bounds__(256) void maxabs_kernel(
    const float* __restrict__ qkv, unsigned* __restrict__ mx) {
  __shared__ float red[256];
  const int seg = blockIdx.x % 3;
  const int row = blockIdx.x / 3;
  const float4* p = (const float4*)(qkv + (size_t)row * F3 + seg * 2048);
  float m = 0.0f;
  for (int i = threadIdx.x; i < 512; i += 256) {
    float4 v = p[i];
    m = fmaxf(m, fmaxf(fmaxf(fabsf(v.x), fabsf(v.y)), fmaxf(fabsf(v.z), fabsf(v.w))));
  }
  red[threadIdx.x] = m;
  __syncthreads();
  for (int s = 128; s > 0; s >>= 1) {
    if (threadIdx.x < s) red[threadIdx.x] = fmaxf(red[threadIdx.x], red[threadIdx.x + s]);
    __syncthreads();
  }
  if (threadIdx.x == 0) atomicMax(mx + seg, __float_as_uint(red[0]));
}

// ---------------------------------------------------------------------------
// Quantize Q,K segments -> fp16 exact e4m3 values, [bh][s][d]
// ---------------------------------------------------------------------------
__global__ __launch_bounds__(256) void quant_qk(
    const float* __restrict__ qkv, const unsigned* __restrict__ mx,
    _Float16* __restrict__ q8, _Float16* __restrict__ k8) {
  const size_t base = ((size_t)blockIdx.x * 256 + threadIdx.x) * 4;
  const int row = (int)(base >> 12);
  const int col = (int)(base & 4095);
  const int seg = col >> 11;
  const int c2 = col & 2047;
  const int h = c2 >> 7, d = c2 & 127;
  const int b = row >> 11, s = row & 2047;
  const float scale = __uint_as_float(mx[seg]) / 448.0f;
  float4 v = *(const float4*)(qkv + (size_t)row * F3 + col);
  H4 r;
  r.h[0] = (_Float16)quant_e4m3(v.x / scale);
  r.h[1] = (_Float16)quant_e4m3(v.y / scale);
  r.h[2] = (_Float16)quant_e4m3(v.z / scale);
  r.h[3] = (_Float16)quant_e4m3(v.w / scale);
  _Float16* dst = seg ? k8 : q8;
  const size_t di = ((size_t)((b * NH + h) * S_) + s) * HD + d;
  *(ushort4*)(dst + di) = r.s4;
}

// ---------------------------------------------------------------------------
// Quantize V -> fp16 values stored TRANSPOSED: v8t[bh][d][s]
// ---------------------------------------------------------------------------
__global__ __launch_bounds__(256) void quant_v_t(
    const float* __restrict__ qkv, const unsigned* __restrict__ mx,
    _Float16* __restrict__ v8t) {
  __shared__ _Float16 tile[64 * 72];
  const int t = threadIdx.x;
  const int bt = blockIdx.x;
  const int dtile = bt & 1;
  const int stile = (bt >> 1) & 31;
  const int bh = bt >> 6;
  const int b = bh >> 4, h = bh & 15;
  const int s0 = stile * 64, d0 = dtile * 64;
  const float scale = __uint_as_float(mx[2]) / 448.0f;

#pragma unroll
  for (int r = 0; r < 4; r++) {
    const int s = s0 + r * 16 + (t >> 4);
    const int dl = (t & 15) * 4;
    float4 v = *(const float4*)(qkv + (size_t)(b * S_ + s) * F3 + 4096 + h * HD + d0 + dl);
    tile[(dl + 0) * 72 + r * 16 + (t >> 4)] = (_Float16)quant_e4m3(v.x / scale);
    tile[(dl + 1) * 72 + r * 16 + (t >> 4)] = (_Float16)quant_e4m3(v.y / scale);
    tile[(dl + 2) * 72 + r * 16 + (t >> 4)] = (_Float16)quant_e4m3(v.z / scale);
    tile[(dl + 3) * 72 + r * 16 + (t >> 4)] = (_Float16)quant_e4m3(v.w / scale);
  }
  __syncthreads();
#pragma unroll
  for (int j = 0; j < 2; j++) {
    const int wi = j * 256 + t;
    const int dl = wi >> 3;
    const int sch = (wi & 7) * 8;
    uint4 val = *(const uint4*)(tile + dl * 72 + sch);
    *(uint4*)(v8t + (size_t)bh * (HD * S_) + (size_t)(d0 + dl) * S_ + s0 + sch) = val;
  }
}

// ---------------------------------------------------------------------------
// MFMA flash attention, round-6 rework:
//  * 32 q per wave (was 64) -> 2048 waves total = 2 waves/SIMD: the chain
//    stalls of one wave overlap the other wave's MFMA/VALU (m114).
//  * register prefetch of next K/V tile (8 uint4/thread) issued right after
//    the LDS-write barrier, consumed next iteration: staging latency hidden.
//  * fixed-base softmax kept (no alpha / no acc rescale).
//  * block = 4 waves (256 thr) = 128 q; grid = 32 bh x 16 = 512 blocks.
// ---------------------------------------------------------------------------
__global__ __launch_bounds__(256, 2) void attn_kernel(
    const _Float16* __restrict__ q8, const _Float16* __restrict__ k8,
    const _Float16* __restrict__ v8t, const unsigned* __restrict__ mx,
    _Float16* __restrict__ oHi, _Float16* __restrict__ oLo) {
  __shared__ __align__(16) char ldsb[35840];
  _Float16* Klds  = (_Float16*)ldsb;                 // [64 keys][136]
  _Float16* VTlds = (_Float16*)(ldsb + 17408);       // [128 d][72]

  const int t = threadIdx.x;        // 0..255
  const int wave = t >> 6;          // 0..3
  const int lane = t & 63;
  const int l31 = lane & 31;
  const int hf = lane >> 5;

  const int qt = blockIdx.x & 15;
  const int bh = blockIdx.x >> 4;
  const int b = bh >> 4, h = bh & 15;
  const int q0 = qt * 128 + wave * 32;   // this wave's 32 queries

  const float qs = __uint_as_float(mx[0]) * (1.0f / 448.0f);
  const float ks = __uint_as_float(mx[1]) * (1.0f / 448.0f);
  const float vs = __uint_as_float(mx[2]) * (1.0f / 448.0f);
  const float sfac = qs * ks * 0.08838834764831843f;   // 1/sqrt(128)

  // Q fragments (B-layout): Q[q=l31][d = st*16 + hf*8 + j]
  f16x8 qf[8];
  {
    const _Float16* qp = q8 + ((size_t)(bh * S_) + q0 + l31) * HD + hf * 8;
#pragma unroll
    for (int st = 0; st < 8; st++)
      qf[st] = *(const f16x8*)(qp + st * 16);
  }

  f32x16 acc[4] = {};
  float m_base = 0.0f;
  float l_run = 0.0f;

  const size_t kB = (size_t)(bh * S_) * HD;
  const size_t vB = (size_t)bh * (HD * S_);
  // per-thread staging coordinates
  const int k_key = t >> 4;            // + r*16
  const int k_dch = (t & 15) * 8;
  const int v_d   = t >> 3;            // + r*32
  const int v_sch = (t & 7) * 8;

  uint4 kp[4], vp[4];
  // prefetch tile 0
#pragma unroll
  for (int r = 0; r < 4; r++)
    kp[r] = *(const uint4*)(k8 + kB + (size_t)(r * 16 + k_key) * HD + k_dch);
#pragma unroll
  for (int r = 0; r < 4; r++)
    vp[r] = *(const uint4*)(v8t + vB + (size_t)(r * 32 + v_d) * S_ + v_sch);

  for (int kt = 0; kt < S_ / 64; kt++) {
    __syncthreads();   // LDS free (previous compute done)
#pragma unroll
    for (int r = 0; r < 4; r++)
      *(uint4*)(Klds + (r * 16 + k_key) * 136 + k_dch) = kp[r];
#pragma unroll
    for (int r = 0; r < 4; r++)
      *(uint4*)(VTlds + (r * 32 + v_d) * 72 + v_sch) = vp[r];
    __syncthreads();

    // issue next tile's loads now; they complete during this tile's compute
    if (kt + 1 < S_ / 64) {
      const int nk = (kt + 1) * 64;
#pragma unroll
      for (int r = 0; r < 4; r++)
        kp[r] = *(const uint4*)(k8 + kB + (size_t)(nk + r * 16 + k_key) * HD + k_dch);
#pragma unroll
      for (int r = 0; r < 4; r++)
        vp[r] = *(const uint4*)(v8t + vB + (size_t)(r * 32 + v_d) * S_ + nk + v_sch);
    }

#pragma unroll
    for (int sub = 0; sub < 2; sub++) {
      const int ksub = sub * 32;
      // ---- S^T = K . Q^T ----
      f32x16 s = {};
#pragma unroll
      for (int st = 0; st < 8; st++) {
        f16x8 af = *(const f16x8*)(Klds + (ksub + l31) * 136 + st * 16 + hf * 8);
        s = __builtin_amdgcn_mfma_f32_32x32x16_f16(af, qf[st], s, 0, 0, 0);
      }
      // ---- fixed-base softmax weights ----
      float p[16];
      if (kt == 0 && sub == 0) {
        float tmax = -3.0e38f;
#pragma unroll
        for (int i = 0; i < 16; i++) {
          p[i] = s[i] * sfac;
          tmax = fmaxf(tmax, p[i]);
        }
        tmax = fmaxf(tmax, __shfl_xor(tmax, 32));
        m_base = tmax;
        float rs = 0.0f;
#pragma unroll
        for (int i = 0; i < 16; i++) {
          p[i] = __expf(p[i] - tmax);
          rs += p[i];
        }
        l_run += rs;
      } else {
        const float mb = m_base;
        float rs = 0.0f;
#pragma unroll
        for (int i = 0; i < 16; i++) {
          p[i] = fminf(__expf(fmaf(s[i], sfac, -mb)), 60000.0f);
          rs += p[i];
        }
        l_run += rs;
      }
      // ---- pack + cross-half exchange -> P^T B-frags (keys ascending) ----
      f16x8 pf[2];
#pragma unroll
      for (int c = 0; c < 2; c++) {
        const int c8 = c * 8;
        const int sidx = hf ? 0 : 4;
        const int oidx = hf ? 4 : 0;
        H2 s0h, s1h, o0h, o1h;
        s0h.h[0] = (_Float16)p[c8 + sidx];     s0h.h[1] = (_Float16)p[c8 + sidx + 1];
        s1h.h[0] = (_Float16)p[c8 + sidx + 2]; s1h.h[1] = (_Float16)p[c8 + sidx + 3];
        o0h.h[0] = (_Float16)p[c8 + oidx];     o0h.h[1] = (_Float16)p[c8 + oidx + 1];
        o1h.h[0] = (_Float16)p[c8 + oidx + 2]; o1h.h[1] = (_Float16)p[c8 + oidx + 3];
        unsigned r0 = (unsigned)__shfl_xor((int)s0h.u, 32);
        unsigned r1 = (unsigned)__shfl_xor((int)s1h.u, 32);
        unsigned fu[4];
        if (hf == 0) { fu[0] = o0h.u; fu[1] = o1h.u; fu[2] = r0; fu[3] = r1; }
        else         { fu[0] = r0;    fu[1] = r1;    fu[2] = o0h.u; fu[3] = o1h.u; }
        pf[c] = *(f16x8*)fu;
      }
      // ---- O^T += V^T . P^T ----
#pragma unroll
      for (int dt = 0; dt < 4; dt++) {
#pragma unroll
        for (int c = 0; c < 2; c++) {
          f16x8 vf = *(const f16x8*)(VTlds + (dt * 32 + l31) * 72 + ksub + c * 16 + hf * 8);
          acc[dt] = __builtin_amdgcn_mfma_f32_32x32x16_f16(vf, pf[c], acc[dt], 0, 0, 0);
        }
      }
    }
  }

  // combine the two half-lane partial sums of l
  l_run += __shfl_xor(l_run, 32);

  // ---- epilogue: O^T -> O via per-wave LDS transpose; emit fp16 hi/lo ----
  __syncthreads();
  float* scr = (float*)ldsb + wave * 1056;   // 32 x 33 fp32 per wave
  const float f = vs / l_run;
#pragma unroll
  for (int dt = 0; dt < 4; dt++) {
#pragma unroll
    for (int i = 0; i < 16; i++) {
      const int dl = (i & 3) + 8 * (i >> 2) + 4 * hf;
      scr[dl * 33 + l31] = acc[dt][i] * f;
    }
    __syncthreads();
#pragma unroll
    for (int g = 0; g < 4; g++) {
      const int idx = g * 64 + lane;
      const int ql = idx >> 3;
      const int dd = (idx & 7) * 4;
      float4 o;
      o.x = scr[(dd + 0) * 33 + ql];
      o.y = scr[(dd + 1) * 33 + ql];
      o.z = scr[(dd + 2) * 33 + ql];
      o.w = scr[(dd + 3) * 33 + ql];
      H4 hh, ll;
      hh.h[0] = (_Float16)o.x; ll.h[0] = (_Float16)(o.x - (float)hh.h[0]);
      hh.h[1] = (_Float16)o.y; ll.h[1] = (_Float16)(o.y - (float)hh.h[1]);
      hh.h[2] = (_Float16)o.z; ll.h[2] = (_Float16)(o.z - (float)hh.h[2]);
      hh.h[3] = (_Float16)o.w; ll.h[3] = (_Float16)(o.w - (float)hh.h[3]);
      const int qg = q0 + ql;
      const size_t ofs = (size_t)(b * S_ + qg) * H_ + h * HD + dt * 32 + dd;
      *(ushort4*)(oHi + ofs) = hh.s4;
      *(ushort4*)(oLo + ofs) = ll.s4;
    }
    __syncthreads();
  }
}

// ---------------------------------------------------------------------------
extern "C" void kernel_launch(void* const* d_in, const int* in_sizes, int n_in,
                              void* d_out, int out_size, void* d_ws, size_t ws_size,
                              hipStream_t stream) {
  const float* x     = (const float*)d_in[0];
  const float* W_qkv = (const float*)d_in[1];
  const float* W_out = (const float*)d_in[2];
  const float* b_out = (const float*)d_in[3];
  float* out = (float*)d_out;

  char* ws = (char*)d_ws;
  // Region 0 [0, 100.66 MB): qkv fp32; later A2 splits (attn output) + B2t
  float*    qkv    = (float*)ws;
  _Float16* A2hi   = (_Float16*)(ws + 33554432);               // 16,777,216 B
  _Float16* A2lo   = (_Float16*)(ws + 50331648);
  _Float16* B2thi  = (_Float16*)(ws + 67108864);               //  8,388,608 B
  _Float16* B2tlo  = (_Float16*)(ws + 75497472);
  // Region 1 [100.66, 151.0 MB): B1t splits, then reused for q8/k8/v8t
  _Float16* B1thi  = (_Float16*)(ws + 100663296);              // 25,165,824 B
  _Float16* B1tlo  = (_Float16*)(ws + 125829120);
  _Float16* q8     = (_Float16*)(ws + 100663296);              // 16,777,216 B
  _Float16* k8     = (_Float16*)(ws + 117440512);
  _Float16* v8t    = (_Float16*)(ws + 134217728);
  // Region 2 [151.0, 184.6 MB): A1 splits
  _Float16* A1hi   = (_Float16*)(ws + 150994944);
  _Float16* A1lo   = (_Float16*)(ws + 167772160);
  unsigned* mx     = (unsigned*)(ws + 184549376);

  hipMemsetAsync(mx, 0, 3 * sizeof(unsigned), stream);

  // split x (A1) and W_qkv^T (B1t)
  split_ab<<<(ROWS * H_) / 1024, 256, 0, stream>>>(x, A1hi, A1lo);
  split_tr<<<dim3(F3 / 64, H_ / 64), 256, 0, stream>>>(W_qkv, B1thi, B1tlo, H_, F3);

  // qkv = x @ W_qkv  (split-fp16 MFMA, K' = 6144)
  gemm_split<<<dim3(F3 / 128, ROWS / 128), 256, 0, stream>>>(
      A1hi, A1lo, B1thi, B1tlo, qkv, nullptr, F3, 0);

  maxabs_kernel<<<ROWS * 3, 256, 0, stream>>>(qkv, mx);
  quant_qk<<<(ROWS * 4096) / 1024, 256, 0, stream>>>(qkv, mx, q8, k8);
  quant_v_t<<<B_ * NH * 32 * 2, 256, 0, stream>>>(qkv, mx, v8t);

  // attention -> writes out-proj A-operand hi/lo directly
  attn_kernel<<<B_ * NH * 16, 256, 0, stream>>>(q8, k8, v8t, mx, A2hi, A2lo);

  // split W_out^T (B2t)
  split_tr<<<dim3(H_ / 64, H_ / 64), 256, 0, stream>>>(W_out, B2thi, B2tlo, H_, H_);

  // out = attn_out @ W_out + b_out
  gemm_split<<<dim3(H_ / 128, ROWS / 128), 256, 0, stream>>>(
      A2hi, A2lo, B2thi, B2tlo, out, b_out, H_, 1);
}